// Round 6
// baseline (441.014 us; speedup 1.0000x reference)
//
#include <hip/hip_runtime.h>
#include <stdint.h>

// Problem constants
#define ENC2 1024   // 2*ENC_HID = K of main GEMM
#define DECH 1024
#define ADIM 1024   // N (attn dim)
#define BB   32
#define SS   1024

typedef _Float16 half_t;
typedef __attribute__((ext_vector_type(8))) _Float16 half8;
typedef __attribute__((ext_vector_type(4))) float    f32x4;

// async global->LDS, 16B per lane; lds dest = wave-uniform base + lane*16
__device__ __forceinline__ void dma16(const half_t* g, half_t* l) {
    __builtin_amdgcn_global_load_lds((const __attribute__((address_space(1))) void*)g,
                                     (__attribute__((address_space(3))) void*)l,
                                     16, 0, 0);
}

// ---------------------------------------------------------------------------
// K_PREP: one dispatch doing three jobs (rounds 1-5 evidence: ~30-35 us fixed
// overhead PER DISPATCH in this harness -> fuse everything).
//  bid   0..255: swizzled fp16 W_enc^T region (nb 0..7, ks 0..31), 128 n-rows
//                x 32 k halfs = 8KB/region; chunk pos = c ^ ((r>>1)&3) so
//                k_main's wave-linear DMA fill yields conflict-free reads.
//  bid 256..383: dp split-K stage 1 (16 col-tiles x 8 k-chunks), writes dpart;
//                stage 2 (sum 8 + bias) is folded into k_main's epilogue.
//  bid 384:      zero the 32 per-batch completion counters for fused softmax.
// ---------------------------------------------------------------------------
__global__ __launch_bounds__(256) void k_prep(const float* __restrict__ W,
                                              const float* __restrict__ dh,
                                              half_t* __restrict__ Wt2,
                                              float* __restrict__ dpart,
                                              int* __restrict__ cnt) {
    __shared__ __align__(16) char sm[32768];
    const int bid = blockIdx.x;
    const int t = threadIdx.x;
    if (bid < 256) {
        float (*tile)[129] = (float(*)[129])sm;   // 32 x 129 floats
        const int nb = bid >> 5, ks = bid & 31;
        #pragma unroll
        for (int i = 0; i < 16; i++) {
            int idx = t + i * 256;
            int kr = idx >> 7, n = idx & 127;
            tile[kr][n] = W[(size_t)(DECH + ks * 32 + kr) * ADIM + nb * 128 + n];
        }
        __syncthreads();
        half_t* reg = Wt2 + ((size_t)(nb * 32 + ks) << 12);   // 4096 halfs
        #pragma unroll
        for (int i = 0; i < 2; i++) {
            int cid = t + i * 256;            // 0..511 chunk id
            int r = cid >> 2, pos = cid & 3;
            int c = pos ^ ((r >> 1) & 3);
            half8 h;
            #pragma unroll
            for (int e = 0; e < 8; e++) h[e] = (half_t)tile[c * 8 + e][r];
            *(half8*)(reg + r * 32 + pos * 8) = h;
        }
    } else if (bid < 384) {
        float (*red)[BB][64] = (float(*)[BB][64])sm;   // [4][32][64]
        const int idx = bid - 256;
        const int ct = idx & 15, kc = idx >> 4;
        const int col = ct * 64 + (t & 63);
        const int w = t >> 6;
        const int k0 = kc * 128 + w * 32;
        float wreg[32];
        #pragma unroll
        for (int kk = 0; kk < 32; kk++)
            wreg[kk] = W[(size_t)(k0 + kk) * ADIM + col];
        float s[BB];
        #pragma unroll
        for (int b = 0; b < BB; b++) s[b] = 0.f;
        #pragma unroll
        for (int kk = 0; kk < 32; kk++) {
            #pragma unroll
            for (int b = 0; b < BB; b++)
                s[b] += dh[b * DECH + k0 + kk] * wreg[kk];
        }
        #pragma unroll
        for (int b = 0; b < BB; b++) red[w][b][t & 63] = s[b];
        __syncthreads();
        if (t < 64) {
            for (int b = 0; b < BB; b++)
                dpart[((size_t)kc * BB + b) * ADIM + ct * 64 + t] =
                    red[0][b][t] + red[1][b][t] + red[2][b][t] + red[3][b][t];
        }
    } else {
        if (t < BB) cnt[t] = 0;
    }
}

// ---------------------------------------------------------------------------
// K_MAIN: fused GEMM(fp16 MFMA) + tanh + dot(v) + (last block) softmax.
// Tile 128x128, BK=32, 256 thr (4 waves, 2x2 of 64x64). Grid 2048 =
// 256 m-tiles x 8 n-tiles; mapping (bid>>6)*8+(bid&7) keeps the 8 blocks
// sharing an A m-tile congruent mod 8 (same XCD) and within 64 bids.
// __launch_bounds__(256,4): cap 128 = 64 AGPR(acc) + 64 arch -> 4 blocks/CU
// (round 5 at 2 blocks/CU: MfmaUtil 19.5% -- barrier drains need more
// co-resident blocks to overlap). LDS 36928B -> 4 blocks fit (148KB/160KB).
// Epilogue folds dp stage-2 (bias + sum of 8 dpart) and softmax: after
// storing this block's 128-row partials, atomicAdd a per-batch counter;
// the 64th arriver (8 mi x 8 nb) acquires and softmaxes the batch row.
// ---------------------------------------------------------------------------
#define BM 128
#define BN 128
#define BK 32
#define LDA 40   // 80B row stride: frag reads/writes land 2/bank (free, m136)

__global__ __launch_bounds__(256, 4) void k_main(const float* __restrict__ enc,
                                                 const half_t* __restrict__ Wt2,
                                                 const float* __restrict__ dpart,
                                                 const float* __restrict__ bias,
                                                 const float* __restrict__ v,
                                                 float* __restrict__ spart,
                                                 int* __restrict__ cnt,
                                                 float* __restrict__ out) {
    __shared__ half_t lsA[2][BM][LDA];    // 20480 B
    __shared__ half_t lsB[2][BN * BK];    // 16384 B, swizzled chunk layout
    __shared__ float sred[8];
    __shared__ int sflag;

    const int bid = blockIdx.x;
    const int mi = (bid >> 6) * 8 + (bid & 7);   // 0..255
    const int nb = (bid >> 3) & 7;               // 0..7
    const int m0 = mi * BM;
    const int n0 = nb * BN;
    const int batch = mi >> 3;                   // 0..31
    const int t = threadIdx.x;
    const int w = t >> 6, L = t & 63;
    const int wm = w & 1, wn = w >> 1;           // 2x2 wave grid, 64x64 tiles
    const int lane15 = L & 15, quad = L >> 4;

    // A staging: thread -> (row, 16-float half-row); 16KB fp32 per buffer
    const int arow = t & 127;
    const int ah   = (t >> 7) * 16;
    const float* Aptr = enc + (size_t)(m0 + arow) * ENC2 + ah;

    const half_t* Bbase = Wt2 + ((size_t)(nb * 32) << 12);

    f32x4 acc[4][4];
    #pragma unroll
    for (int i = 0; i < 4; i++)
        #pragma unroll
        for (int j = 0; j < 4; j++) acc[i][j] = (f32x4)0.f;

    float4 ra[4];
    half8 rh0, rh1;
    auto loadA = [&](int ks) {
        const float* p = Aptr + ks * BK;
        ra[0] = ((const float4*)p)[0];
        ra[1] = ((const float4*)p)[1];
        ra[2] = ((const float4*)p)[2];
        ra[3] = ((const float4*)p)[3];
    };
    auto cvtA = [&]() {   // 16 f32 -> 16 f16; frees ra, rh live across barrier
        half8 h0, h1;
        h0[0] = (half_t)ra[0].x; h0[1] = (half_t)ra[0].y;
        h0[2] = (half_t)ra[0].z; h0[3] = (half_t)ra[0].w;
        h0[4] = (half_t)ra[1].x; h0[5] = (half_t)ra[1].y;
        h0[6] = (half_t)ra[1].z; h0[7] = (half_t)ra[1].w;
        h1[0] = (half_t)ra[2].x; h1[1] = (half_t)ra[2].y;
        h1[2] = (half_t)ra[2].z; h1[3] = (half_t)ra[2].w;
        h1[4] = (half_t)ra[3].x; h1[5] = (half_t)ra[3].y;
        h1[6] = (half_t)ra[3].z; h1[7] = (half_t)ra[3].w;
        rh0 = h0; rh1 = h1;
    };
    auto writeA = [&](int pb) {
        *(half8*)&lsA[pb][arow][ah]     = rh0;
        *(half8*)&lsA[pb][arow][ah + 8] = rh1;
    };
    auto dmaB = [&](int ks, int pb) {
        #pragma unroll
        for (int jj = 0; jj < 2; jj++) {
            int j = 2 * w + jj;   // 8KB region: 8 x 1KB DMA, 2 per wave
            dma16(Bbase + ((size_t)ks << 12) + j * 512 + L * 8,
                  &lsB[pb][j * 512]);
        }
    };

    // prologue
    loadA(0);
    dmaB(0, 0);
    cvtA(); writeA(0);
    loadA(1);
    __syncthreads();

    for (int ks = 0; ks < ENC2 / BK; ks++) {
        const int cur = ks & 1;
        if (ks < ENC2 / BK - 1) {
            dmaB(ks + 1, cur ^ 1);    // issue DMA before the cvt stall
            cvtA();                   // waits on loadA(ks+1)
            writeA(cur ^ 1);
            if (ks < ENC2 / BK - 2) loadA(ks + 2);
        }
        half8 af[4], bf[4];
        #pragma unroll
        for (int sm2 = 0; sm2 < 4; sm2++)
            af[sm2] = *(const half8*)&lsA[cur][wm * 64 + sm2 * 16 + lane15][quad * 8];
        #pragma unroll
        for (int sn = 0; sn < 4; sn++) {
            int r = wn * 64 + sn * 16 + lane15;
            int pos = quad ^ ((r >> 1) & 3);
            bf[sn] = *(const half8*)&lsB[cur][r * 32 + pos * 8];
        }
        #pragma unroll
        for (int sm2 = 0; sm2 < 4; sm2++)
            #pragma unroll
            for (int sn = 0; sn < 4; sn++)
                acc[sm2][sn] = __builtin_amdgcn_mfma_f32_16x16x32_f16(
                    af[sm2], bf[sn], acc[sm2][sn], 0, 0, 0);
        __syncthreads();
    }

    // epilogue constants: dp = bias + sum of 8 split-K partials (dp stage 2)
    float vv[4], dp[4];
    #pragma unroll
    for (int sn = 0; sn < 4; sn++) {
        int ng = n0 + wn * 64 + sn * 16 + lane15;
        vv[sn] = v[ng];
        float d = bias[ng];
        #pragma unroll
        for (int kc = 0; kc < 8; kc++)
            d += dpart[((size_t)kc * BB + batch) * ADIM + ng];
        dp[sn] = d;
    }

    // tanh(acc + dp) . v; shuffle-reduce 16 col-lanes, LDS-reduce across wn
    // C/D layout: row(m) = quad*4 + reg, col(n) = lane15
    float* redL = (float*)&lsA[0][0][0];   // [wn][128], buffer dead post-loop
    #pragma unroll
    for (int sm2 = 0; sm2 < 4; sm2++) {
        #pragma unroll
        for (int rr = 0; rr < 4; rr++) {
            float s = 0.f;
            #pragma unroll
            for (int sn = 0; sn < 4; sn++) {
                float x = acc[sm2][sn][rr] + dp[sn];
                float e  = __builtin_amdgcn_exp2f(x * 2.8853900817779268f);
                float th = 1.f - 2.f * __builtin_amdgcn_rcpf(e + 1.f);
                s += th * vv[sn];
            }
            s += __shfl_xor(s, 1, 64);
            s += __shfl_xor(s, 2, 64);
            s += __shfl_xor(s, 4, 64);
            s += __shfl_xor(s, 8, 64);
            if (lane15 == 0) {
                int mlocal = wm * 64 + sm2 * 16 + quad * 4 + rr;
                redL[wn * 128 + mlocal] = s;
            }
        }
    }
    __syncthreads();
    if (t < 128)
        spart[((size_t)nb << 15) + m0 + t] = redL[t] + redL[128 + t];
    __syncthreads();

    // fused softmax: 64 blocks per batch (8 mi x 8 nb); last arriver runs it
    if (t == 0) {
        __threadfence();                               // release spart stores
        sflag = (atomicAdd(&cnt[batch], 1) == 63);     // device-scope (m20)
    }
    __syncthreads();
    if (sflag) {
        __threadfence();                               // acquire all spart
        float x[4];
        #pragma unroll
        for (int i = 0; i < 4; i++) {
            size_t off = (size_t)batch * SS + t + i * 256;
            float s = 0.f;
            #pragma unroll
            for (int n2 = 0; n2 < 8; n2++)
                s += spart[((size_t)n2 << 15) + off];
            x[i] = s;
        }
        float mx = fmaxf(fmaxf(x[0], x[1]), fmaxf(x[2], x[3]));
        #pragma unroll
        for (int d = 1; d < 64; d <<= 1) mx = fmaxf(mx, __shfl_xor(mx, d, 64));
        if ((t & 63) == 0) sred[t >> 6] = mx;
        __syncthreads();
        mx = fmaxf(fmaxf(sred[0], sred[1]), fmaxf(sred[2], sred[3]));
        float e[4], s = 0.f;
        #pragma unroll
        for (int i = 0; i < 4; i++) {
            e[i] = __builtin_amdgcn_exp2f((x[i] - mx) * 1.4426950408889634f);
            s += e[i];
        }
        #pragma unroll
        for (int d = 1; d < 64; d <<= 1) s += __shfl_xor(s, d, 64);
        if ((t & 63) == 0) sred[4 + (t >> 6)] = s;
        __syncthreads();
        s = sred[4] + sred[5] + sred[6] + sred[7];
        float inv = 1.f / s;
        #pragma unroll
        for (int i = 0; i < 4; i++)
            out[(size_t)batch * SS + t + i * 256] = e[i] * inv;
    }
}

// ---------------------------------------------------------------------------
extern "C" void kernel_launch(void* const* d_in, const int* in_sizes, int n_in,
                              void* d_out, int out_size, void* d_ws, size_t ws_size,
                              hipStream_t stream) {
    const float* dh   = (const float*)d_in[0];  // (32,1024)
    const float* enc  = (const float*)d_in[1];  // (32,1024,1024)
    const float* W    = (const float*)d_in[2];  // (2048,1024)
    const float* bias = (const float*)d_in[3];  // (1024,)
    const float* v    = (const float*)d_in[4];  // (1024,)
    float* out = (float*)d_out;

    char* ws = (char*)d_ws;
    half_t* Wt2   = (half_t*)ws;                          // 2 MB
    float*  dpart = (float*)(ws + (2u << 20));            // 1 MB (8 kc x 32 b x 1024)
    float*  spart = (float*)(ws + (3u << 20));            // 1 MB (8 nb x 32768)
    int*    cnt   = (int*)(ws + (4u << 20));              // 128 B

    k_prep<<<385,  256, 0, stream>>>(W, dh, Wt2, dpart, cnt);
    k_main<<<2048, 256, 0, stream>>>(enc, Wt2, dpart, bias, v, spart, cnt, out);
}

// Round 7
// 403.963 us; speedup vs baseline: 1.0917x; 1.0917x over previous
//
#include <hip/hip_runtime.h>
#include <stdint.h>

// Problem constants
#define ENC2 1024   // 2*ENC_HID = K of main GEMM
#define DECH 1024
#define ADIM 1024   // N (attn dim)
#define BB   32
#define SS   1024

typedef _Float16 half_t;
typedef __attribute__((ext_vector_type(8))) _Float16 half8;
typedef __attribute__((ext_vector_type(4))) float    f32x4;

// async global->LDS, 16B per lane; lds dest = wave-uniform base + lane*16
__device__ __forceinline__ void dma16(const void* g, void* l) {
    __builtin_amdgcn_global_load_lds((const __attribute__((address_space(1))) void*)g,
                                     (__attribute__((address_space(3))) void*)l,
                                     16, 0, 0);
}

// ---------------------------------------------------------------------------
// K_PREP (unchanged from round 6 — passed):
//  bid   0..255: swizzled fp16 W_enc^T region (nb 0..7, ks 0..31), 128 rows x
//                32 halfs, chunk pos = c ^ ((r>>1)&3).
//  bid 256..383: dp split-K stage 1 -> dpart (stage 2 folded into k_main).
//  bid 384:      zero 32 per-batch completion counters.
// ---------------------------------------------------------------------------
__global__ __launch_bounds__(256) void k_prep(const float* __restrict__ W,
                                              const float* __restrict__ dh,
                                              half_t* __restrict__ Wt2,
                                              float* __restrict__ dpart,
                                              int* __restrict__ cnt) {
    __shared__ __align__(16) char sm[32768];
    const int bid = blockIdx.x;
    const int t = threadIdx.x;
    if (bid < 256) {
        float (*tile)[129] = (float(*)[129])sm;
        const int nb = bid >> 5, ks = bid & 31;
        #pragma unroll
        for (int i = 0; i < 16; i++) {
            int idx = t + i * 256;
            int kr = idx >> 7, n = idx & 127;
            tile[kr][n] = W[(size_t)(DECH + ks * 32 + kr) * ADIM + nb * 128 + n];
        }
        __syncthreads();
        half_t* reg = Wt2 + ((size_t)(nb * 32 + ks) << 12);   // 4096 halfs
        #pragma unroll
        for (int i = 0; i < 2; i++) {
            int cid = t + i * 256;
            int r = cid >> 2, pos = cid & 3;
            int c = pos ^ ((r >> 1) & 3);
            half8 h;
            #pragma unroll
            for (int e = 0; e < 8; e++) h[e] = (half_t)tile[c * 8 + e][r];
            *(half8*)(reg + r * 32 + pos * 8) = h;
        }
    } else if (bid < 384) {
        float (*red)[BB][64] = (float(*)[BB][64])sm;
        const int idx = bid - 256;
        const int ct = idx & 15, kc = idx >> 4;
        const int col = ct * 64 + (t & 63);
        const int w = t >> 6;
        const int k0 = kc * 128 + w * 32;
        float wreg[32];
        #pragma unroll
        for (int kk = 0; kk < 32; kk++)
            wreg[kk] = W[(size_t)(k0 + kk) * ADIM + col];
        float s[BB];
        #pragma unroll
        for (int b = 0; b < BB; b++) s[b] = 0.f;
        #pragma unroll
        for (int kk = 0; kk < 32; kk++) {
            #pragma unroll
            for (int b = 0; b < BB; b++)
                s[b] += dh[b * DECH + k0 + kk] * wreg[kk];
        }
        #pragma unroll
        for (int b = 0; b < BB; b++) red[w][b][t & 63] = s[b];
        __syncthreads();
        if (t < 64) {
            for (int b = 0; b < BB; b++)
                dpart[((size_t)kc * BB + b) * ADIM + ct * 64 + t] =
                    red[0][b][t] + red[1][b][t] + red[2][b][t] + red[3][b][t];
        }
    } else {
        if (t < BB) cnt[t] = 0;
    }
}

// ---------------------------------------------------------------------------
// K_MAIN: fused GEMM + tanh + dot(v) + (last block per batch) softmax.
// Pure m97-structure K-loop: BOTH A and B staged by global_load_lds — no
// global->VGPR round-trip anywhere (rounds 4-6 evidence: the vmcnt(0) barrier
// drain of the in-flight A VGPR prefetch was the latency bottleneck; DMA-only
// staging is the structure measured at 874 TF on this chip).
// A is fp32 in LDS; its DMA *source* addresses are XOR-permuted per lane
// (chunk c = s ^ (row&7), within one 128B segment -> still coalesced) so the
// wave-linear fill lands a swizzled layout whose fragment ds_read_b128s are
// conflict-free (each quarter-wave: 8 slots x 2 lanes). f32->f16 convert
// happens at fragment-read time (~48 VALU/wave-iter, hides under MFMA).
// Tile 128x128, BK=32, 256 thr (2x2 waves of 64x64). Grid 2048 = 256 mi x
// 8 nb; mapping keeps the 8 A-sharers congruent mod 8 (same XCD).
// LDS 49KB -> 3 blocks/CU.
// ---------------------------------------------------------------------------
#define BM 128
#define BN 128
#define BK 32

__global__ __launch_bounds__(256, 3) void k_main(const float* __restrict__ enc,
                                                 const half_t* __restrict__ Wt2,
                                                 const float* __restrict__ dpart,
                                                 const float* __restrict__ bias,
                                                 const float* __restrict__ v,
                                                 float* __restrict__ spart,
                                                 int* __restrict__ cnt,
                                                 float* __restrict__ out) {
    __shared__ float  lsA[2][BM * BK];    // 16 KB each, swizzled fp32 chunks
    __shared__ half_t lsB[2][BN * BK];    // 8 KB each, swizzled fp16 chunks
    __shared__ float sred[8];
    __shared__ int sflag;

    const int bid = blockIdx.x;
    const int mi = (bid >> 6) * 8 + (bid & 7);   // 0..255
    const int nb = (bid >> 3) & 7;               // 0..7
    const int m0 = mi * BM;
    const int n0 = nb * BN;
    const int batch = mi >> 3;                   // 0..31
    const int t = threadIdx.x;
    const int w = t >> 6, L = t & 63;
    const int wm = w & 1, wn = w >> 1;           // 2x2 wave grid, 64x64 tiles
    const int lane15 = L & 15, quad = L >> 4;

    // A DMA: fill j (0..15) covers rows 8j..8j+7; lane -> row 8j+(L>>3),
    // slot s = L&7 holds global chunk c = s ^ ((L>>3)&7)  (4 floats = 16B)
    const int arow8 = L >> 3;                 // 0..7 within fill
    const int achk  = (L & 7) ^ (arow8 & 7);  // source chunk for this lane
    const half_t* Bbase = Wt2 + ((size_t)(nb * 32) << 12);

    f32x4 acc[4][4];
    #pragma unroll
    for (int i = 0; i < 4; i++)
        #pragma unroll
        for (int j = 0; j < 4; j++) acc[i][j] = (f32x4)0.f;

    auto dmaA = [&](int ks, int pb) {
        #pragma unroll
        for (int jj = 0; jj < 4; jj++) {
            int j = w * 4 + jj;               // 16 fills x 1KB
            int row = j * 8 + arow8;
            const float* g = enc + (size_t)(m0 + row) * ENC2 + ks * BK + achk * 4;
            dma16(g, &lsA[pb][j * 256]);
        }
    };
    auto dmaB = [&](int ks, int pb) {
        #pragma unroll
        for (int jj = 0; jj < 2; jj++) {
            int j = 2 * w + jj;               // 8 fills x 1KB
            dma16(Bbase + ((size_t)ks << 12) + j * 512 + L * 8,
                  &lsB[pb][j * 512]);
        }
    };

    // prologue
    dmaA(0, 0);
    dmaB(0, 0);
    __syncthreads();

    const int swA = lane15 & 7;   // (frag row & 7) — fragment A slot xor
    for (int ks = 0; ks < ENC2 / BK; ks++) {
        const int cur = ks & 1;
        if (ks < ENC2 / BK - 1) {
            dmaA(ks + 1, cur ^ 1);
            dmaB(ks + 1, cur ^ 1);
        }
        half8 af[4], bf[4];
        #pragma unroll
        for (int sm2 = 0; sm2 < 4; sm2++) {
            int r = wm * 64 + sm2 * 16 + lane15;
            const float* base = &lsA[cur][r * 32];
            f32x4 p0 = *(const f32x4*)(base + (((2 * quad)     ^ swA) << 2));
            f32x4 p1 = *(const f32x4*)(base + (((2 * quad + 1) ^ swA) << 2));
            half8 h;
            h[0] = (half_t)p0[0]; h[1] = (half_t)p0[1];
            h[2] = (half_t)p0[2]; h[3] = (half_t)p0[3];
            h[4] = (half_t)p1[0]; h[5] = (half_t)p1[1];
            h[6] = (half_t)p1[2]; h[7] = (half_t)p1[3];
            af[sm2] = h;
        }
        #pragma unroll
        for (int sn = 0; sn < 4; sn++) {
            int r = wn * 64 + sn * 16 + lane15;
            int pos = quad ^ ((r >> 1) & 3);
            bf[sn] = *(const half8*)&lsB[cur][r * 32 + pos * 8];
        }
        #pragma unroll
        for (int sm2 = 0; sm2 < 4; sm2++)
            #pragma unroll
            for (int sn = 0; sn < 4; sn++)
                acc[sm2][sn] = __builtin_amdgcn_mfma_f32_16x16x32_f16(
                    af[sm2], bf[sn], acc[sm2][sn], 0, 0, 0);
        __syncthreads();
    }

    // epilogue constants: dp = bias + sum of 8 split-K partials
    float vv[4], dp[4];
    #pragma unroll
    for (int sn = 0; sn < 4; sn++) {
        int ng = n0 + wn * 64 + sn * 16 + lane15;
        vv[sn] = v[ng];
        float d = bias[ng];
        #pragma unroll
        for (int kc = 0; kc < 8; kc++)
            d += dpart[((size_t)kc * BB + batch) * ADIM + ng];
        dp[sn] = d;
    }

    // tanh(acc + dp) . v; shuffle-reduce 16 col-lanes, LDS-reduce across wn
    // C/D layout: row(m) = quad*4 + reg, col(n) = lane15
    float* redL = (float*)&lsA[0][0];   // [wn][128], buffer dead post-loop
    #pragma unroll
    for (int sm2 = 0; sm2 < 4; sm2++) {
        #pragma unroll
        for (int rr = 0; rr < 4; rr++) {
            float s = 0.f;
            #pragma unroll
            for (int sn = 0; sn < 4; sn++) {
                float x = acc[sm2][sn][rr] + dp[sn];
                float e  = __builtin_amdgcn_exp2f(x * 2.8853900817779268f);
                float th = 1.f - 2.f * __builtin_amdgcn_rcpf(e + 1.f);
                s += th * vv[sn];
            }
            s += __shfl_xor(s, 1, 64);
            s += __shfl_xor(s, 2, 64);
            s += __shfl_xor(s, 4, 64);
            s += __shfl_xor(s, 8, 64);
            if (lane15 == 0) {
                int mlocal = wm * 64 + sm2 * 16 + quad * 4 + rr;
                redL[wn * 128 + mlocal] = s;
            }
        }
    }
    __syncthreads();
    if (t < 128)
        spart[((size_t)nb << 15) + m0 + t] = redL[t] + redL[128 + t];
    __syncthreads();

    // fused softmax: 64 blocks per batch (8 mi x 8 nb); last arriver runs it
    if (t == 0) {
        __threadfence();                               // release spart stores
        sflag = (atomicAdd(&cnt[batch], 1) == 63);     // device-scope (m20)
    }
    __syncthreads();
    if (sflag) {
        __threadfence();                               // acquire all spart
        float x[4];
        #pragma unroll
        for (int i = 0; i < 4; i++) {
            size_t off = (size_t)batch * SS + t + i * 256;
            float s = 0.f;
            #pragma unroll
            for (int n2 = 0; n2 < 8; n2++)
                s += spart[((size_t)n2 << 15) + off];
            x[i] = s;
        }
        float mx = fmaxf(fmaxf(x[0], x[1]), fmaxf(x[2], x[3]));
        #pragma unroll
        for (int d = 1; d < 64; d <<= 1) mx = fmaxf(mx, __shfl_xor(mx, d, 64));
        if ((t & 63) == 0) sred[t >> 6] = mx;
        __syncthreads();
        mx = fmaxf(fmaxf(sred[0], sred[1]), fmaxf(sred[2], sred[3]));
        float e[4], s = 0.f;
        #pragma unroll
        for (int i = 0; i < 4; i++) {
            e[i] = __builtin_amdgcn_exp2f((x[i] - mx) * 1.4426950408889634f);
            s += e[i];
        }
        #pragma unroll
        for (int d = 1; d < 64; d <<= 1) s += __shfl_xor(s, d, 64);
        if ((t & 63) == 0) sred[4 + (t >> 6)] = s;
        __syncthreads();
        s = sred[4] + sred[5] + sred[6] + sred[7];
        float inv = 1.f / s;
        #pragma unroll
        for (int i = 0; i < 4; i++)
            out[(size_t)batch * SS + t + i * 256] = e[i] * inv;
    }
}

// ---------------------------------------------------------------------------
extern "C" void kernel_launch(void* const* d_in, const int* in_sizes, int n_in,
                              void* d_out, int out_size, void* d_ws, size_t ws_size,
                              hipStream_t stream) {
    const float* dh   = (const float*)d_in[0];  // (32,1024)
    const float* enc  = (const float*)d_in[1];  // (32,1024,1024)
    const float* W    = (const float*)d_in[2];  // (2048,1024)
    const float* bias = (const float*)d_in[3];  // (1024,)
    const float* v    = (const float*)d_in[4];  // (1024,)
    float* out = (float*)d_out;

    char* ws = (char*)d_ws;
    half_t* Wt2   = (half_t*)ws;                          // 2 MB
    float*  dpart = (float*)(ws + (2u << 20));            // 1 MB
    float*  spart = (float*)(ws + (3u << 20));            // 1 MB
    int*    cnt   = (int*)(ws + (4u << 20));              // 128 B

    k_prep<<<385,  256, 0, stream>>>(W, dh, Wt2, dpart, cnt);
    k_main<<<2048, 256, 0, stream>>>(enc, Wt2, dpart, bias, v, spart, cnt, out);
}